// Round 2
// baseline (25099.701 us; speedup 1.0000x reference)
//
#include <hip/hip_runtime.h>
#include <stdint.h>

#define Tt 128
#define OBSd 768
#define ACTd 7
#define OUTFd 3584                 // 512 deter + 1024 stoch + 1024 prior + 1024 post
#define OUT_ROW (Tt * OUTFd)       // floats per batch row
#define TC 16                      // prior batch chunk (timesteps)
#define NBLK 256                   // persistent grid: 1 block per CU

// ---------------------------------------------------------------------------
// Threefry-2x32, exact JAX semantics (identical to round-1 — do not touch)
// ---------------------------------------------------------------------------
__device__ __forceinline__ uint32_t rotl32(uint32_t v, int r) {
  return (v << r) | (v >> (32 - r));
}

__device__ __forceinline__ void tf2x32(uint32_t key0, uint32_t key1,
                                       uint32_t x0, uint32_t x1,
                                       uint32_t& o0, uint32_t& o1) {
  uint32_t ks0 = key0, ks1 = key1, ks2 = key0 ^ key1 ^ 0x1BD11BDAu;
  x0 += ks0; x1 += ks1;
#define TFR(r) { x0 += x1; x1 = rotl32(x1, (r)); x1 ^= x0; }
  TFR(13) TFR(15) TFR(26) TFR(6)
  x0 += ks1; x1 += ks2 + 1u;
  TFR(17) TFR(29) TFR(16) TFR(24)
  x0 += ks2; x1 += ks0 + 2u;
  TFR(13) TFR(15) TFR(26) TFR(6)
  x0 += ks0; x1 += ks1 + 3u;
  TFR(17) TFR(29) TFR(16) TFR(24)
  x0 += ks1; x1 += ks2 + 4u;
  TFR(13) TFR(15) TFR(26) TFR(6)
  x0 += ks2; x1 += ks0 + 5u;
#undef TFR
  o0 = x0; o1 = x1;
}

__global__ __launch_bounds__(128) void keys_k(uint32_t* keys) {
  const int t = threadIdx.x;
  uint32_t o0, o1;
  tf2x32(0u, 42u, 0u, (uint32_t)t, o0, o1);
  keys[2 * t] = o0;
  keys[2 * t + 1] = o1;
}

// ---------------------------------------------------------------------------
// Hand-rolled grid barrier (sense-reversing, agent scope).
// Equivalent semantics to cg::grid_group::sync but needs NO cooperative
// launch (which the harness's stream capture rejected silently last round).
// Agent-scope acq/rel atomics emit the buffer_wbl2/buffer_inv cache ops that
// make normal stores visible across XCD L2s.
// ---------------------------------------------------------------------------
__device__ __forceinline__ void gbar(uint32_t* cnt, uint32_t* sense,
                                     uint32_t* lsense_sh) {
  __syncthreads();
  if (threadIdx.x == 0) {
    const uint32_t s = *lsense_sh ^ 1u;
    *lsense_sh = s;
    const uint32_t arrived =
        __hip_atomic_fetch_add(cnt, 1u, __ATOMIC_ACQ_REL,
                               __HIP_MEMORY_SCOPE_AGENT);
    if (arrived == NBLK - 1u) {
      __hip_atomic_store(cnt, 0u, __ATOMIC_RELAXED, __HIP_MEMORY_SCOPE_AGENT);
      __hip_atomic_store(sense, s, __ATOMIC_RELEASE, __HIP_MEMORY_SCOPE_AGENT);
    } else {
      while (__hip_atomic_load(sense, __ATOMIC_ACQUIRE,
                               __HIP_MEMORY_SCOPE_AGENT) != s) {
        __builtin_amdgcn_s_sleep(1);
      }
    }
  }
  __syncthreads();
}

// ---------------------------------------------------------------------------
// Persistent kernel: the entire T=128 sequential loop.
// 256 blocks x 256 threads (1 block/CU). Per step, 3 phases with grid barriers:
//   A: GRU   — gh = dprev @ w_hh (f64) + one-hot gather gi + gates -> deter
//      tile 16 rows x 32 cols, 256 blocks (all CUs busy)
//   B: post1 — h1po = ELU([deter|obs_t] @ qw1 + qb1), K=1280, 256 blocks
//   C: post2 — logits = h1po @ qw2 + qb2 + gumbel-argmax sample (verbatim math)
// All K-loops use register-prefetch double buffering to hide global latency.
// ---------------------------------------------------------------------------
__global__ __launch_bounds__(256) void loop_k(
    const float* __restrict__ obs, const float* __restrict__ act,
    const float* __restrict__ w_ih, const float* __restrict__ w_hh,
    const float* __restrict__ b_ih, const float* __restrict__ b_hh,
    const float* __restrict__ qw1, const float* __restrict__ qb1,
    const float* __restrict__ qw2, const float* __restrict__ qb2,
    const uint32_t* __restrict__ keys,
    double* __restrict__ deterA, double* __restrict__ deterB,
    double* __restrict__ h1po, int* __restrict__ sidx,
    float* __restrict__ sval, float* __restrict__ out,
    uint32_t* bar_cnt, uint32_t* bar_sense) {
  const int bid = blockIdx.x;
  const int tid = threadIdx.x;
  const int tx = tid & 15, ty = tid >> 4;

  __shared__ uint32_t lsense;
  if (tid == 0) lsense = 0u;

  // phase A shared
  __shared__ double Aa[16][17];
  __shared__ double Wr[16][32], Wz[16][32], Wn[16][32];
  __shared__ int   sIdxL[16][32];
  __shared__ float sValL[16][32];
  __shared__ float actL[16][8];
  // phase B shared
  __shared__ double Ba[16][17];
  __shared__ double Bw[16][32];
  // phase C shared
  __shared__ double Ca[16][34];
  __shared__ double Cw[16][32];
  __shared__ double Ls[32][33];
  __shared__ int bcS[32];

  __syncthreads();   // publish lsense init

  for (int t = 0; t < Tt; ++t) {
    double* dp = (t & 1) ? deterB : deterA;
    double* dn = (t & 1) ? deterA : deterB;

    // ================= phase A : GRU =================
    {
      const int row0 = (bid >> 4) * 16;
      const int col0 = (bid & 15) * 32;
      // stage sample indices/values + actions for this block's 16 rows
      {
        const int e = tid * 2;
        const int bl = e >> 5, s = e & 31;
        const int2 iv = *(const int2*)(sidx + (row0 + bl) * 32 + s);
        sIdxL[bl][s] = iv.x; sIdxL[bl][s + 1] = iv.y;
        const float2 fv = *(const float2*)(sval + (row0 + bl) * 32 + s);
        sValL[bl][s] = fv.x; sValL[bl][s + 1] = fv.y;
        if (tid < 112) {
          const int bl2 = tid / 7, j2 = tid % 7;
          actL[bl2][j2] = act[((size_t)(row0 + bl2) * Tt + t) * ACTd + j2];
        }
      }
      double aR[2] = {}, aZ[2] = {}, aNi[2] = {}, aNh[2] = {};
      const int nW = tx * 2;
      // prefetch k0 = 0
      double pA = dp[(size_t)(row0 + ty) * 512 + tx];
      float2 pr, pz, pn;
      {
        const size_t wb = (size_t)ty * 1536 + col0 + nW;
        pr = *(const float2*)(w_hh + wb);
        pz = *(const float2*)(w_hh + wb + 512);
        pn = *(const float2*)(w_hh + wb + 1024);
      }
      for (int k0 = 0; k0 < 512; k0 += 16) {
        Aa[tx][ty] = pA;
        Wr[ty][nW] = pr.x; Wr[ty][nW + 1] = pr.y;
        Wz[ty][nW] = pz.x; Wz[ty][nW + 1] = pz.y;
        Wn[ty][nW] = pn.x; Wn[ty][nW + 1] = pn.y;
        __syncthreads();
        if (k0 + 16 < 512) {
          pA = dp[(size_t)(row0 + ty) * 512 + k0 + 16 + tx];
          const size_t wb = (size_t)(k0 + 16 + ty) * 1536 + col0 + nW;
          pr = *(const float2*)(w_hh + wb);
          pz = *(const float2*)(w_hh + wb + 512);
          pn = *(const float2*)(w_hh + wb + 1024);
        }
#pragma unroll
        for (int kk = 0; kk < 16; ++kk) {
          const double a = Aa[kk][ty];
          const double2 wr = *(const double2*)&Wr[kk][2 * tx];
          const double2 wz = *(const double2*)&Wz[kk][2 * tx];
          const double2 wn = *(const double2*)&Wn[kk][2 * tx];
          aR[0] = fma(a, wr.x, aR[0]);   aR[1] = fma(a, wr.y, aR[1]);
          aZ[0] = fma(a, wz.x, aZ[0]);   aZ[1] = fma(a, wz.y, aZ[1]);
          aNh[0] = fma(a, wn.x, aNh[0]); aNh[1] = fma(a, wn.y, aNh[1]);
        }
        __syncthreads();
      }
      // gi gather: stoch is one-hot (forward value 1.0 to within 1e-16)
      for (int s = 0; s < 32; ++s) {
        const float v = sValL[ty][s];
        if (v != 0.0f) {
          const size_t wb = (size_t)(s * 32 + sIdxL[ty][s]) * 1536 + col0 + 2 * tx;
          const float2 f0 = *(const float2*)(w_ih + wb);
          const float2 f1 = *(const float2*)(w_ih + wb + 512);
          const float2 f2 = *(const float2*)(w_ih + wb + 1024);
          const double dv = (double)v;
          aR[0]  = fma(dv, (double)f0.x, aR[0]);  aR[1]  = fma(dv, (double)f0.y, aR[1]);
          aZ[0]  = fma(dv, (double)f1.x, aZ[0]);  aZ[1]  = fma(dv, (double)f1.y, aZ[1]);
          aNi[0] = fma(dv, (double)f2.x, aNi[0]); aNi[1] = fma(dv, (double)f2.y, aNi[1]);
        }
      }
      for (int j2 = 0; j2 < 7; ++j2) {
        const double av = (double)actL[ty][j2];
        const size_t wb = (size_t)(1024 + j2) * 1536 + col0 + 2 * tx;
        const float2 f0 = *(const float2*)(w_ih + wb);
        const float2 f1 = *(const float2*)(w_ih + wb + 512);
        const float2 f2 = *(const float2*)(w_ih + wb + 1024);
        aR[0]  = fma(av, (double)f0.x, aR[0]);  aR[1]  = fma(av, (double)f0.y, aR[1]);
        aZ[0]  = fma(av, (double)f1.x, aZ[0]);  aZ[1]  = fma(av, (double)f1.y, aZ[1]);
        aNi[0] = fma(av, (double)f2.x, aNi[0]); aNi[1] = fma(av, (double)f2.y, aNi[1]);
      }
      // gates
      {
        const int b = row0 + ty;
        const size_t obase = (size_t)b * OUT_ROW + (size_t)t * OUTFd;
#pragma unroll
        for (int cb = 0; cb < 2; ++cb) {
          const int jj = col0 + 2 * tx + cb;
          const double dold = dp[(size_t)b * 512 + jj];
          const double xr = aR[cb] + (double)b_ih[jj] + (double)b_hh[jj];
          const double xz = aZ[cb] + (double)b_ih[512 + jj] + (double)b_hh[512 + jj];
          const double r = 1.0 / (1.0 + exp(-xr));
          const double z = 1.0 / (1.0 + exp(-xz));
          const double n = tanh(aNi[cb] + (double)b_ih[1024 + jj] +
                                r * (aNh[cb] + (double)b_hh[1024 + jj]));
          const double dnv = (1.0 - z) * n + z * dold;
          dn[(size_t)b * 512 + jj] = dnv;
          out[obase + jj] = (float)dnv;
        }
      }
    }
    gbar(bar_cnt, bar_sense, &lsense);

    // ================= phase B : post1 =================
    {
      const int row0 = (bid >> 4) * 16;
      const int col0 = (bid & 15) * 32;
      const int nW = tx * 2;
      double a0 = 0.0, a1 = 0.0;
      // prefetch k0 = 0 (k<512 -> deter part)
      double pA = dn[(size_t)(row0 + ty) * 512 + tx];
      float2 pW = *(const float2*)(qw1 + (size_t)ty * 512 + col0 + nW);
      for (int k0 = 0; k0 < 1280; k0 += 16) {
        Ba[tx][ty] = pA;
        Bw[ty][nW] = (double)pW.x; Bw[ty][nW + 1] = (double)pW.y;
        __syncthreads();
        if (k0 + 16 < 1280) {
          const int gc = k0 + 16 + tx;
          const int gr = row0 + ty;
          pA = (gc < 512)
                   ? dn[(size_t)gr * 512 + gc]
                   : (double)obs[((size_t)gr * Tt + t) * OBSd + (gc - 512)];
          pW = *(const float2*)(qw1 + (size_t)(k0 + 16 + ty) * 512 + col0 + nW);
        }
#pragma unroll
        for (int kk = 0; kk < 16; ++kk) {
          const double a = Ba[kk][ty];
          const double2 w = *(const double2*)&Bw[kk][2 * tx];
          a0 = fma(a, w.x, a0);
          a1 = fma(a, w.y, a1);
        }
        __syncthreads();
      }
      const int cc = col0 + 2 * tx;
      double v0 = a0 + (double)qb1[cc];
      double v1 = a1 + (double)qb1[cc + 1];
      v0 = v0 > 0.0 ? v0 : expm1(v0);
      v1 = v1 > 0.0 ? v1 : expm1(v1);
      double* o = h1po + (size_t)(row0 + ty) * 512 + cc;
      o[0] = v0; o[1] = v1;
    }
    gbar(bar_cnt, bar_sense, &lsense);

    // ================= phase C : post2 + sample =================
    {
      const int row0 = (bid >> 5) * 32;
      const int s = bid & 31;
      const int col0 = s * 32;
      const int sA = tid * 2;
      const int kkA = sA & 15, mA = sA >> 4;
      const int kkW = sA >> 5, nW2 = sA & 31;
      double a00 = 0, a01 = 0, a10 = 0, a11 = 0;
      double2 pH = *(const double2*)(h1po + (size_t)(row0 + mA) * 512 + kkA);
      float2 pW = *(const float2*)(qw2 + (size_t)kkW * 1024 + col0 + nW2);
      for (int k0 = 0; k0 < 512; k0 += 16) {
        Ca[kkA][mA] = pH.x; Ca[kkA + 1][mA] = pH.y;
        Cw[kkW][nW2] = (double)pW.x; Cw[kkW][nW2 + 1] = (double)pW.y;
        __syncthreads();
        if (k0 + 16 < 512) {
          pH = *(const double2*)(h1po + (size_t)(row0 + mA) * 512 + k0 + 16 + kkA);
          pW = *(const float2*)(qw2 + (size_t)(k0 + 16 + kkW) * 1024 + col0 + nW2);
        }
#pragma unroll
        for (int kk = 0; kk < 16; ++kk) {
          const double2 av = *(const double2*)&Ca[kk][2 * ty];
          const double2 wv2 = *(const double2*)&Cw[kk][2 * tx];
          a00 = fma(av.x, wv2.x, a00); a01 = fma(av.x, wv2.y, a01);
          a10 = fma(av.y, wv2.x, a10); a11 = fma(av.y, wv2.y, a11);
        }
        __syncthreads();
      }
      const uint32_t key0 = keys[2 * t], key1 = keys[2 * t + 1];
      double accv[2][2] = {{a00, a01}, {a10, a11}};
#pragma unroll
      for (int rb = 0; rb < 2; ++rb) {
        const int b = row0 + 2 * ty + rb;
#pragma unroll
        for (int cb = 0; cb < 2; ++cb) {
          const int col = col0 + 2 * tx + cb;
          const double l = accv[rb][cb] + (double)qb2[col];
          out[(size_t)b * OUT_ROW + (size_t)t * OUTFd + 2560 + col] = (float)l;
          // gumbel — EXACT round-1 formula (matches reference sampling bits)
          uint32_t o0, o1;
          tf2x32(key0, key1, 0u, (uint32_t)(b * 1024 + col), o0, o1);
          const uint32_t bits = o0 ^ o1;
          const uint32_t m = bits >> 9;
          const float uf = __uint_as_float(m | 0x3f800000u) - 1.0f;
          const double u = (m == 0u) ? (double)1.17549435e-38f : (double)uf;
          const double g = -log(-log(u));
          Ls[2 * ty + rb][2 * tx + cb] = l + g;
        }
      }
      __syncthreads();
      if (tid < 32) {
        const int bl = tid;
        double best = -1.0e300;
        int bc = 0;
        for (int c = 0; c < 32; ++c) {
          const double v = Ls[bl][c];
          if (v > best) { best = v; bc = c; }   // strict >: first-index ties
        }
        bcS[bl] = bc;
        const int b = row0 + bl;
        sidx[b * 32 + s] = bc;
        sval[b * 32 + s] = 1.0f;
      }
      __syncthreads();
#pragma unroll
      for (int rb = 0; rb < 2; ++rb) {
        const int b = row0 + 2 * ty + rb;
        const int bc = bcS[2 * ty + rb];
#pragma unroll
        for (int cb = 0; cb < 2; ++cb) {
          const int c = 2 * tx + cb;
          out[(size_t)b * OUT_ROW + (size_t)t * OUTFd + 512 + col0 + c] =
              (c == bc) ? 1.0f : 0.0f;
        }
      }
    }
    gbar(bar_cnt, bar_sense, &lsense);
  }
}

// ---------------------------------------------------------------------------
// Deferred prior head, f32, batched over (b, t) chunks of TC timesteps.
// prior1: h = ELU(deter @ pw1 + pb1)   [4096 x 512], deter read from d_out
// prior2: logits = h @ pw2 + pb2       [4096 x 1024] -> d_out prior block
// 64x64 tile, 256 threads, 4x4 per thread. (unchanged, verified)
// ---------------------------------------------------------------------------
__global__ __launch_bounds__(256) void prior1_k(const float* __restrict__ outbase,
                                                const float* __restrict__ pw1,
                                                const float* __restrict__ pb1,
                                                float* __restrict__ hbuf, int tbase) {
  __shared__ float As[16][68];
  __shared__ float Ws[16][64];
  const int tid = threadIdx.x;
  const int tx = tid & 15, ty = tid >> 4;
  const int row0 = blockIdx.y * 64, col0 = blockIdx.x * 64;
  float acc[4][4] = {};
  const int sA = tid * 4;
  const int kkA = sA & 15, mA = sA >> 4;
  const int kkW = tid >> 4, nW = (tid & 15) * 4;
  const int grow = row0 + mA;
  const int b = grow >> 4, tt = tbase + (grow & 15);
  const float* arow = outbase + (size_t)b * OUT_ROW + (size_t)tt * OUTFd;
  for (int k0 = 0; k0 < 512; k0 += 16) {
    const float4 av = *(const float4*)(arow + k0 + kkA);
    As[kkA][mA] = av.x; As[kkA + 1][mA] = av.y;
    As[kkA + 2][mA] = av.z; As[kkA + 3][mA] = av.w;
    *(float4*)&Ws[kkW][nW] = *(const float4*)(pw1 + (size_t)(k0 + kkW) * 512 + col0 + nW);
    __syncthreads();
#pragma unroll
    for (int kk = 0; kk < 16; ++kk) {
      const float4 a = *(const float4*)&As[kk][4 * ty];
      const float4 w = *(const float4*)&Ws[kk][4 * tx];
      const float aa[4] = {a.x, a.y, a.z, a.w};
      const float ww[4] = {w.x, w.y, w.z, w.w};
#pragma unroll
      for (int i = 0; i < 4; ++i)
#pragma unroll
        for (int j = 0; j < 4; ++j) acc[i][j] = fmaf(aa[i], ww[j], acc[i][j]);
    }
    __syncthreads();
  }
#pragma unroll
  for (int i = 0; i < 4; ++i) {
    const int r = row0 + 4 * ty + i;
#pragma unroll
    for (int j = 0; j < 4; ++j) {
      const int c = col0 + 4 * tx + j;
      float x = acc[i][j] + pb1[c];
      x = x > 0.f ? x : expm1f(x);
      hbuf[(size_t)r * 512 + c] = x;
    }
  }
}

__global__ __launch_bounds__(256) void prior2_k(const float* __restrict__ hbuf,
                                                const float* __restrict__ pw2,
                                                const float* __restrict__ pb2,
                                                float* __restrict__ outbase, int tbase) {
  __shared__ float As[16][68];
  __shared__ float Ws[16][64];
  const int tid = threadIdx.x;
  const int tx = tid & 15, ty = tid >> 4;
  const int row0 = blockIdx.y * 64, col0 = blockIdx.x * 64;
  float acc[4][4] = {};
  const int sA = tid * 4;
  const int kkA = sA & 15, mA = sA >> 4;
  const int kkW = tid >> 4, nW = (tid & 15) * 4;
  for (int k0 = 0; k0 < 512; k0 += 16) {
    const float4 av = *(const float4*)(hbuf + (size_t)(row0 + mA) * 512 + k0 + kkA);
    As[kkA][mA] = av.x; As[kkA + 1][mA] = av.y;
    As[kkA + 2][mA] = av.z; As[kkA + 3][mA] = av.w;
    *(float4*)&Ws[kkW][nW] = *(const float4*)(pw2 + (size_t)(k0 + kkW) * 1024 + col0 + nW);
    __syncthreads();
#pragma unroll
    for (int kk = 0; kk < 16; ++kk) {
      const float4 a = *(const float4*)&As[kk][4 * ty];
      const float4 w = *(const float4*)&Ws[kk][4 * tx];
      const float aa[4] = {a.x, a.y, a.z, a.w};
      const float ww[4] = {w.x, w.y, w.z, w.w};
#pragma unroll
      for (int i = 0; i < 4; ++i)
#pragma unroll
        for (int j = 0; j < 4; ++j) acc[i][j] = fmaf(aa[i], ww[j], acc[i][j]);
    }
    __syncthreads();
  }
#pragma unroll
  for (int i = 0; i < 4; ++i) {
    const int grow = row0 + 4 * ty + i;
    const int b = grow >> 4, tt = tbase + (grow & 15);
    float* orow = outbase + (size_t)b * OUT_ROW + (size_t)tt * OUTFd + 1536;
#pragma unroll
    for (int j = 0; j < 4; ++j) {
      const int c = col0 + 4 * tx + j;
      orow[c] = acc[i][j] + pb2[c];
    }
  }
}

// ---------------------------------------------------------------------------
extern "C" void kernel_launch(void* const* d_in, const int* in_sizes, int n_in,
                              void* d_out, int out_size, void* d_ws, size_t ws_size,
                              hipStream_t stream) {
  const float* obs  = (const float*)d_in[0];
  const float* act  = (const float*)d_in[1];
  const float* w_ih = (const float*)d_in[2];
  const float* w_hh = (const float*)d_in[3];
  const float* b_ih = (const float*)d_in[4];
  const float* b_hh = (const float*)d_in[5];
  const float* pw1  = (const float*)d_in[6];
  const float* pb1  = (const float*)d_in[7];
  const float* pw2  = (const float*)d_in[8];
  const float* pb2  = (const float*)d_in[9];
  const float* qw1  = (const float*)d_in[10];
  const float* qb1  = (const float*)d_in[11];
  const float* qw2  = (const float*)d_in[12];
  const float* qb2  = (const float*)d_in[13];
  float* out = (float*)d_out;
  char* ws = (char*)d_ws;

  // workspace layout
  double*   deterA = (double*)(ws + 0);                 // 1 MiB
  double*   deterB = (double*)(ws + (1u << 20));        // 1 MiB
  double*   h1po   = (double*)(ws + (2u << 20));        // 1 MiB
  int*      sidx   = (int*)(ws + (3u << 20));           // 32 KiB
  float*    sval   = (float*)(ws + (3u << 20) + 32768); // 32 KiB
  uint32_t* keys   = (uint32_t*)(ws + (3u << 20) + 65536); // 1 KiB
  uint32_t* bar    = (uint32_t*)(ws + (3u << 20) + 66560); // 256 B barrier state
  float*    hbuf   = (float*)(ws + (4u << 20));         // 8 MiB (4096x512 f32)

  uint32_t* bar_cnt   = bar;       // [0]
  uint32_t* bar_sense = bar + 32;  // separate cacheline

  hipMemsetAsync(deterA, 0, 256 * 512 * 8, stream);
  hipMemsetAsync(sidx, 0, 256 * 32 * 4, stream);
  hipMemsetAsync(sval, 0, 256 * 32 * 4, stream);
  hipMemsetAsync(bar, 0, 256, stream);
  keys_k<<<1, 128, 0, stream>>>(keys);

  // whole sequential loop in ONE persistent kernel: 256 blocks (1/CU),
  // normal launch (graph-capture-safe), hand-rolled grid barrier.
  loop_k<<<dim3(NBLK), dim3(256), 0, stream>>>(
      obs, act, w_ih, w_hh, b_ih, b_hh, qw1, qb1, qw2, qb2, keys,
      deterA, deterB, h1po, sidx, sval, out, bar_cnt, bar_sense);

  // deferred prior head (f32), batched over 8 chunks of TC=16 timesteps
  for (int c = 0; c < Tt / TC; ++c) {
    prior1_k<<<dim3(8, 64), 256, 0, stream>>>(out, pw1, pb1, hbuf, c * TC);
    prior2_k<<<dim3(16, 64), 256, 0, stream>>>(hbuf, pw2, pb2, out, c * TC);
  }
}

// Round 3
// 20749.480 us; speedup vs baseline: 1.2097x; 1.2097x over previous
//
#include <hip/hip_runtime.h>
#include <stdint.h>

#define Tt 128
#define OBSd 768
#define ACTd 7
#define OUTFd 3584                 // 512 deter + 1024 stoch + 1024 prior + 1024 post
#define OUT_ROW (Tt * OUTFd)       // floats per batch row
#define TC 16                      // prior batch chunk (timesteps)
#define NBLK 256                   // persistent grid: 1 block per CU

// ---------------------------------------------------------------------------
// Threefry-2x32, exact JAX semantics (identical to round-1 — do not touch)
// ---------------------------------------------------------------------------
__device__ __forceinline__ uint32_t rotl32(uint32_t v, int r) {
  return (v << r) | (v >> (32 - r));
}

__device__ __forceinline__ void tf2x32(uint32_t key0, uint32_t key1,
                                       uint32_t x0, uint32_t x1,
                                       uint32_t& o0, uint32_t& o1) {
  uint32_t ks0 = key0, ks1 = key1, ks2 = key0 ^ key1 ^ 0x1BD11BDAu;
  x0 += ks0; x1 += ks1;
#define TFR(r) { x0 += x1; x1 = rotl32(x1, (r)); x1 ^= x0; }
  TFR(13) TFR(15) TFR(26) TFR(6)
  x0 += ks1; x1 += ks2 + 1u;
  TFR(17) TFR(29) TFR(16) TFR(24)
  x0 += ks2; x1 += ks0 + 2u;
  TFR(13) TFR(15) TFR(26) TFR(6)
  x0 += ks0; x1 += ks1 + 3u;
  TFR(17) TFR(29) TFR(16) TFR(24)
  x0 += ks1; x1 += ks2 + 4u;
  TFR(13) TFR(15) TFR(26) TFR(6)
  x0 += ks2; x1 += ks0 + 5u;
#undef TFR
  o0 = x0; o1 = x1;
}

__global__ __launch_bounds__(128) void keys_k(uint32_t* keys) {
  const int t = threadIdx.x;
  uint32_t o0, o1;
  tf2x32(0u, 42u, 0u, (uint32_t)t, o0, o1);
  keys[2 * t] = o0;
  keys[2 * t + 1] = o1;
}

// ---------------------------------------------------------------------------
// Relaxed agent-scope (sc1, coherent-point) accessors for cross-phase data.
// All inter-block data in loop_k goes through these, so the grid barrier
// needs NO release/acquire fences (no buffer_wbl2 / buffer_inv storms that
// round 2's ACQ_REL barrier caused: they cost ~150 us/step and evicted the
// L2-resident weights -> 2x HBM over-fetch).
// ---------------------------------------------------------------------------
__device__ __forceinline__ double ald(const double* p) {
  return __hip_atomic_load((double*)p, __ATOMIC_RELAXED, __HIP_MEMORY_SCOPE_AGENT);
}
__device__ __forceinline__ void ast(double* p, double v) {
  __hip_atomic_store(p, v, __ATOMIC_RELAXED, __HIP_MEMORY_SCOPE_AGENT);
}
__device__ __forceinline__ float alf(const float* p) {
  return __hip_atomic_load((float*)p, __ATOMIC_RELAXED, __HIP_MEMORY_SCOPE_AGENT);
}
__device__ __forceinline__ void asf(float* p, float v) {
  __hip_atomic_store(p, v, __ATOMIC_RELAXED, __HIP_MEMORY_SCOPE_AGENT);
}
__device__ __forceinline__ int ali(const int* p) {
  return __hip_atomic_load((int*)p, __ATOMIC_RELAXED, __HIP_MEMORY_SCOPE_AGENT);
}
__device__ __forceinline__ void asi(int* p, int v) {
  __hip_atomic_store(p, v, __ATOMIC_RELAXED, __HIP_MEMORY_SCOPE_AGENT);
}

// ---------------------------------------------------------------------------
// Grid barrier, fence-free: sense-reversing counter, relaxed atomics only.
// Correctness: s_waitcnt vmcnt(0) before arrival ensures this block's sc1
// data stores reached the coherence point; master orders cnt-reset before
// sense-flip with another vmcnt(0); waiters' post-barrier sc1 loads read the
// coherence point directly (no stale L1/L2 copies possible for sc1 ops).
// ---------------------------------------------------------------------------
__device__ __forceinline__ void gbar(uint32_t* cnt, uint32_t* sense,
                                     uint32_t* lsense_sh) {
  __syncthreads();
  if (threadIdx.x == 0) {
    asm volatile("s_waitcnt vmcnt(0)" ::: "memory");
    const uint32_t s = *lsense_sh ^ 1u;
    *lsense_sh = s;
    const uint32_t arrived =
        __hip_atomic_fetch_add(cnt, 1u, __ATOMIC_RELAXED,
                               __HIP_MEMORY_SCOPE_AGENT);
    if (arrived == NBLK - 1u) {
      __hip_atomic_store(cnt, 0u, __ATOMIC_RELAXED, __HIP_MEMORY_SCOPE_AGENT);
      asm volatile("s_waitcnt vmcnt(0)" ::: "memory");
      __hip_atomic_store(sense, s, __ATOMIC_RELAXED, __HIP_MEMORY_SCOPE_AGENT);
    } else {
      while (__hip_atomic_load(sense, __ATOMIC_RELAXED,
                               __HIP_MEMORY_SCOPE_AGENT) != s) {
        __builtin_amdgcn_s_sleep(1);
      }
    }
  }
  __syncthreads();
}

// ---------------------------------------------------------------------------
// Persistent kernel: the entire T=128 sequential loop.
// 256 blocks x 256 threads (1 block/CU). Per step, 3 phases with grid barriers:
//   A: GRU   — gh = dprev @ w_hh (f64) + one-hot gather gi + gates -> deter
//   B: post1 — h1po = ELU([deter|obs_t] @ qw1 + qb1), K=1280
//   C: post2 — logits = h1po @ qw2 + qb2 + gumbel-argmax sample (verbatim math)
// ---------------------------------------------------------------------------
__global__ __launch_bounds__(256) void loop_k(
    const float* __restrict__ obs, const float* __restrict__ act,
    const float* __restrict__ w_ih, const float* __restrict__ w_hh,
    const float* __restrict__ b_ih, const float* __restrict__ b_hh,
    const float* __restrict__ qw1, const float* __restrict__ qb1,
    const float* __restrict__ qw2, const float* __restrict__ qb2,
    const uint32_t* __restrict__ keys,
    double* __restrict__ deterA, double* __restrict__ deterB,
    double* __restrict__ h1po, int* __restrict__ sidx,
    float* __restrict__ sval, float* __restrict__ out,
    uint32_t* bar_cnt, uint32_t* bar_sense) {
  const int bid = blockIdx.x;
  const int tid = threadIdx.x;
  const int tx = tid & 15, ty = tid >> 4;

  __shared__ uint32_t lsense;
  if (tid == 0) lsense = 0u;

  // phase A shared
  __shared__ double Aa[16][17];
  __shared__ double Wr[16][32], Wz[16][32], Wn[16][32];
  __shared__ int   sIdxL[16][32];
  __shared__ float sValL[16][32];
  __shared__ float actL[16][8];
  // phase B shared
  __shared__ double Ba[16][17];
  __shared__ double Bw[16][32];
  // phase C shared
  __shared__ double Ca[16][34];
  __shared__ double Cw[16][32];
  __shared__ double Ls[32][33];
  __shared__ int bcS[32];

  __syncthreads();   // publish lsense init

  for (int t = 0; t < Tt; ++t) {
    double* dp = (t & 1) ? deterB : deterA;
    double* dn = (t & 1) ? deterA : deterB;

    // ================= phase A : GRU =================
    {
      const int row0 = (bid >> 4) * 16;
      const int col0 = (bid & 15) * 32;
      // stage sample indices/values + actions for this block's 16 rows
      {
        const int e = tid * 2;
        const int bl = e >> 5, s = e & 31;
        sIdxL[bl][s]     = ali(sidx + (row0 + bl) * 32 + s);
        sIdxL[bl][s + 1] = ali(sidx + (row0 + bl) * 32 + s + 1);
        sValL[bl][s]     = alf(sval + (row0 + bl) * 32 + s);
        sValL[bl][s + 1] = alf(sval + (row0 + bl) * 32 + s + 1);
        if (tid < 112) {
          const int bl2 = tid / 7, j2 = tid % 7;
          actL[bl2][j2] = act[((size_t)(row0 + bl2) * Tt + t) * ACTd + j2];
        }
      }
      double aR[2] = {}, aZ[2] = {}, aNi[2] = {}, aNh[2] = {};
      const int nW = tx * 2;
      // prefetch k0 = 0
      double pA = ald(dp + (size_t)(row0 + ty) * 512 + tx);
      float2 pr, pz, pn;
      {
        const size_t wb = (size_t)ty * 1536 + col0 + nW;
        pr = *(const float2*)(w_hh + wb);
        pz = *(const float2*)(w_hh + wb + 512);
        pn = *(const float2*)(w_hh + wb + 1024);
      }
      for (int k0 = 0; k0 < 512; k0 += 16) {
        Aa[tx][ty] = pA;
        Wr[ty][nW] = pr.x; Wr[ty][nW + 1] = pr.y;
        Wz[ty][nW] = pz.x; Wz[ty][nW + 1] = pz.y;
        Wn[ty][nW] = pn.x; Wn[ty][nW + 1] = pn.y;
        __syncthreads();
        if (k0 + 16 < 512) {
          pA = ald(dp + (size_t)(row0 + ty) * 512 + k0 + 16 + tx);
          const size_t wb = (size_t)(k0 + 16 + ty) * 1536 + col0 + nW;
          pr = *(const float2*)(w_hh + wb);
          pz = *(const float2*)(w_hh + wb + 512);
          pn = *(const float2*)(w_hh + wb + 1024);
        }
#pragma unroll
        for (int kk = 0; kk < 16; ++kk) {
          const double a = Aa[kk][ty];
          const double2 wr = *(const double2*)&Wr[kk][2 * tx];
          const double2 wz = *(const double2*)&Wz[kk][2 * tx];
          const double2 wn = *(const double2*)&Wn[kk][2 * tx];
          aR[0] = fma(a, wr.x, aR[0]);   aR[1] = fma(a, wr.y, aR[1]);
          aZ[0] = fma(a, wz.x, aZ[0]);   aZ[1] = fma(a, wz.y, aZ[1]);
          aNh[0] = fma(a, wn.x, aNh[0]); aNh[1] = fma(a, wn.y, aNh[1]);
        }
        __syncthreads();
      }
      // gi gather: stoch is one-hot (forward value 1.0 to within 1e-16)
      for (int s = 0; s < 32; ++s) {
        const float v = sValL[ty][s];
        if (v != 0.0f) {
          const size_t wb = (size_t)(s * 32 + sIdxL[ty][s]) * 1536 + col0 + 2 * tx;
          const float2 f0 = *(const float2*)(w_ih + wb);
          const float2 f1 = *(const float2*)(w_ih + wb + 512);
          const float2 f2 = *(const float2*)(w_ih + wb + 1024);
          const double dv = (double)v;
          aR[0]  = fma(dv, (double)f0.x, aR[0]);  aR[1]  = fma(dv, (double)f0.y, aR[1]);
          aZ[0]  = fma(dv, (double)f1.x, aZ[0]);  aZ[1]  = fma(dv, (double)f1.y, aZ[1]);
          aNi[0] = fma(dv, (double)f2.x, aNi[0]); aNi[1] = fma(dv, (double)f2.y, aNi[1]);
        }
      }
      for (int j2 = 0; j2 < 7; ++j2) {
        const double av = (double)actL[ty][j2];
        const size_t wb = (size_t)(1024 + j2) * 1536 + col0 + 2 * tx;
        const float2 f0 = *(const float2*)(w_ih + wb);
        const float2 f1 = *(const float2*)(w_ih + wb + 512);
        const float2 f2 = *(const float2*)(w_ih + wb + 1024);
        aR[0]  = fma(av, (double)f0.x, aR[0]);  aR[1]  = fma(av, (double)f0.y, aR[1]);
        aZ[0]  = fma(av, (double)f1.x, aZ[0]);  aZ[1]  = fma(av, (double)f1.y, aZ[1]);
        aNi[0] = fma(av, (double)f2.x, aNi[0]); aNi[1] = fma(av, (double)f2.y, aNi[1]);
      }
      // gates
      {
        const int b = row0 + ty;
        const size_t obase = (size_t)b * OUT_ROW + (size_t)t * OUTFd;
#pragma unroll
        for (int cb = 0; cb < 2; ++cb) {
          const int jj = col0 + 2 * tx + cb;
          const double dold = ald(dp + (size_t)b * 512 + jj);
          const double xr = aR[cb] + (double)b_ih[jj] + (double)b_hh[jj];
          const double xz = aZ[cb] + (double)b_ih[512 + jj] + (double)b_hh[512 + jj];
          const double r = 1.0 / (1.0 + exp(-xr));
          const double z = 1.0 / (1.0 + exp(-xz));
          const double n = tanh(aNi[cb] + (double)b_ih[1024 + jj] +
                                r * (aNh[cb] + (double)b_hh[1024 + jj]));
          const double dnv = (1.0 - z) * n + z * dold;
          ast(dn + (size_t)b * 512 + jj, dnv);
          out[obase + jj] = (float)dnv;
        }
      }
    }
    gbar(bar_cnt, bar_sense, &lsense);

    // ================= phase B : post1 =================
    {
      const int row0 = (bid >> 4) * 16;
      const int col0 = (bid & 15) * 32;
      const int nW = tx * 2;
      double a0 = 0.0, a1 = 0.0;
      // prefetch k0 = 0 (k<512 -> deter part)
      double pA = ald(dn + (size_t)(row0 + ty) * 512 + tx);
      float2 pW = *(const float2*)(qw1 + (size_t)ty * 512 + col0 + nW);
      for (int k0 = 0; k0 < 1280; k0 += 16) {
        Ba[tx][ty] = pA;
        Bw[ty][nW] = (double)pW.x; Bw[ty][nW + 1] = (double)pW.y;
        __syncthreads();
        if (k0 + 16 < 1280) {
          const int gc = k0 + 16 + tx;
          const int gr = row0 + ty;
          pA = (gc < 512)
                   ? ald(dn + (size_t)gr * 512 + gc)
                   : (double)obs[((size_t)gr * Tt + t) * OBSd + (gc - 512)];
          pW = *(const float2*)(qw1 + (size_t)(k0 + 16 + ty) * 512 + col0 + nW);
        }
#pragma unroll
        for (int kk = 0; kk < 16; ++kk) {
          const double a = Ba[kk][ty];
          const double2 w = *(const double2*)&Bw[kk][2 * tx];
          a0 = fma(a, w.x, a0);
          a1 = fma(a, w.y, a1);
        }
        __syncthreads();
      }
      const int cc = col0 + 2 * tx;
      double v0 = a0 + (double)qb1[cc];
      double v1 = a1 + (double)qb1[cc + 1];
      v0 = v0 > 0.0 ? v0 : expm1(v0);
      v1 = v1 > 0.0 ? v1 : expm1(v1);
      ast(h1po + (size_t)(row0 + ty) * 512 + cc, v0);
      ast(h1po + (size_t)(row0 + ty) * 512 + cc + 1, v1);
    }
    gbar(bar_cnt, bar_sense, &lsense);

    // ================= phase C : post2 + sample =================
    {
      const int row0 = (bid >> 5) * 32;
      const int s = bid & 31;
      const int col0 = s * 32;
      const int sA = tid * 2;
      const int kkA = sA & 15, mA = sA >> 4;
      const int kkW = sA >> 5, nW2 = sA & 31;
      double a00 = 0, a01 = 0, a10 = 0, a11 = 0;
      double pH0 = ald(h1po + (size_t)(row0 + mA) * 512 + kkA);
      double pH1 = ald(h1po + (size_t)(row0 + mA) * 512 + kkA + 1);
      float2 pW = *(const float2*)(qw2 + (size_t)kkW * 1024 + col0 + nW2);
      for (int k0 = 0; k0 < 512; k0 += 16) {
        Ca[kkA][mA] = pH0; Ca[kkA + 1][mA] = pH1;
        Cw[kkW][nW2] = (double)pW.x; Cw[kkW][nW2 + 1] = (double)pW.y;
        __syncthreads();
        if (k0 + 16 < 512) {
          pH0 = ald(h1po + (size_t)(row0 + mA) * 512 + k0 + 16 + kkA);
          pH1 = ald(h1po + (size_t)(row0 + mA) * 512 + k0 + 16 + kkA + 1);
          pW = *(const float2*)(qw2 + (size_t)(k0 + 16 + kkW) * 1024 + col0 + nW2);
        }
#pragma unroll
        for (int kk = 0; kk < 16; ++kk) {
          const double2 av = *(const double2*)&Ca[kk][2 * ty];
          const double2 wv2 = *(const double2*)&Cw[kk][2 * tx];
          a00 = fma(av.x, wv2.x, a00); a01 = fma(av.x, wv2.y, a01);
          a10 = fma(av.y, wv2.x, a10); a11 = fma(av.y, wv2.y, a11);
        }
        __syncthreads();
      }
      const uint32_t key0 = keys[2 * t], key1 = keys[2 * t + 1];
      double accv[2][2] = {{a00, a01}, {a10, a11}};
#pragma unroll
      for (int rb = 0; rb < 2; ++rb) {
        const int b = row0 + 2 * ty + rb;
#pragma unroll
        for (int cb = 0; cb < 2; ++cb) {
          const int col = col0 + 2 * tx + cb;
          const double l = accv[rb][cb] + (double)qb2[col];
          out[(size_t)b * OUT_ROW + (size_t)t * OUTFd + 2560 + col] = (float)l;
          // gumbel — EXACT round-1 formula (matches reference sampling bits)
          uint32_t o0, o1;
          tf2x32(key0, key1, 0u, (uint32_t)(b * 1024 + col), o0, o1);
          const uint32_t bits = o0 ^ o1;
          const uint32_t m = bits >> 9;
          const float uf = __uint_as_float(m | 0x3f800000u) - 1.0f;
          const double u = (m == 0u) ? (double)1.17549435e-38f : (double)uf;
          const double g = -log(-log(u));
          Ls[2 * ty + rb][2 * tx + cb] = l + g;
        }
      }
      __syncthreads();
      if (tid < 32) {
        const int bl = tid;
        double best = -1.0e300;
        int bc = 0;
        for (int c = 0; c < 32; ++c) {
          const double v = Ls[bl][c];
          if (v > best) { best = v; bc = c; }   // strict >: first-index ties
        }
        bcS[bl] = bc;
        const int b = row0 + bl;
        asi(sidx + b * 32 + s, bc);
        asf(sval + b * 32 + s, 1.0f);
      }
      __syncthreads();
#pragma unroll
      for (int rb = 0; rb < 2; ++rb) {
        const int b = row0 + 2 * ty + rb;
        const int bc = bcS[2 * ty + rb];
#pragma unroll
        for (int cb = 0; cb < 2; ++cb) {
          const int c = 2 * tx + cb;
          out[(size_t)b * OUT_ROW + (size_t)t * OUTFd + 512 + col0 + c] =
              (c == bc) ? 1.0f : 0.0f;
        }
      }
    }
    if (t != Tt - 1) gbar(bar_cnt, bar_sense, &lsense);
  }
}

// ---------------------------------------------------------------------------
// Deferred prior head, f32, batched over (b, t) chunks of TC timesteps.
// prior1: h = ELU(deter @ pw1 + pb1)   [4096 x 512], deter read from d_out
// prior2: logits = h @ pw2 + pb2       [4096 x 1024] -> d_out prior block
// 64x64 tile, 256 threads, 4x4 per thread. (unchanged, verified)
// ---------------------------------------------------------------------------
__global__ __launch_bounds__(256) void prior1_k(const float* __restrict__ outbase,
                                                const float* __restrict__ pw1,
                                                const float* __restrict__ pb1,
                                                float* __restrict__ hbuf, int tbase) {
  __shared__ float As[16][68];
  __shared__ float Ws[16][64];
  const int tid = threadIdx.x;
  const int tx = tid & 15, ty = tid >> 4;
  const int row0 = blockIdx.y * 64, col0 = blockIdx.x * 64;
  float acc[4][4] = {};
  const int sA = tid * 4;
  const int kkA = sA & 15, mA = sA >> 4;
  const int kkW = tid >> 4, nW = (tid & 15) * 4;
  const int grow = row0 + mA;
  const int b = grow >> 4, tt = tbase + (grow & 15);
  const float* arow = outbase + (size_t)b * OUT_ROW + (size_t)tt * OUTFd;
  for (int k0 = 0; k0 < 512; k0 += 16) {
    const float4 av = *(const float4*)(arow + k0 + kkA);
    As[kkA][mA] = av.x; As[kkA + 1][mA] = av.y;
    As[kkA + 2][mA] = av.z; As[kkA + 3][mA] = av.w;
    *(float4*)&Ws[kkW][nW] = *(const float4*)(pw1 + (size_t)(k0 + kkW) * 512 + col0 + nW);
    __syncthreads();
#pragma unroll
    for (int kk = 0; kk < 16; ++kk) {
      const float4 a = *(const float4*)&As[kk][4 * ty];
      const float4 w = *(const float4*)&Ws[kk][4 * tx];
      const float aa[4] = {a.x, a.y, a.z, a.w};
      const float ww[4] = {w.x, w.y, w.z, w.w};
#pragma unroll
      for (int i = 0; i < 4; ++i)
#pragma unroll
        for (int j = 0; j < 4; ++j) acc[i][j] = fmaf(aa[i], ww[j], acc[i][j]);
    }
    __syncthreads();
  }
#pragma unroll
  for (int i = 0; i < 4; ++i) {
    const int r = row0 + 4 * ty + i;
#pragma unroll
    for (int j = 0; j < 4; ++j) {
      const int c = col0 + 4 * tx + j;
      float x = acc[i][j] + pb1[c];
      x = x > 0.f ? x : expm1f(x);
      hbuf[(size_t)r * 512 + c] = x;
    }
  }
}

__global__ __launch_bounds__(256) void prior2_k(const float* __restrict__ hbuf,
                                                const float* __restrict__ pw2,
                                                const float* __restrict__ pb2,
                                                float* __restrict__ outbase, int tbase) {
  __shared__ float As[16][68];
  __shared__ float Ws[16][64];
  const int tid = threadIdx.x;
  const int tx = tid & 15, ty = tid >> 4;
  const int row0 = blockIdx.y * 64, col0 = blockIdx.x * 64;
  float acc[4][4] = {};
  const int sA = tid * 4;
  const int kkA = sA & 15, mA = sA >> 4;
  const int kkW = tid >> 4, nW = (tid & 15) * 4;
  for (int k0 = 0; k0 < 512; k0 += 16) {
    const float4 av = *(const float4*)(hbuf + (size_t)(row0 + mA) * 512 + k0 + kkA);
    As[kkA][mA] = av.x; As[kkA + 1][mA] = av.y;
    As[kkA + 2][mA] = av.z; As[kkA + 3][mA] = av.w;
    *(float4*)&Ws[kkW][nW] = *(const float4*)(pw2 + (size_t)(k0 + kkW) * 1024 + col0 + nW);
    __syncthreads();
#pragma unroll
    for (int kk = 0; kk < 16; ++kk) {
      const float4 a = *(const float4*)&As[kk][4 * ty];
      const float4 w = *(const float4*)&Ws[kk][4 * tx];
      const float aa[4] = {a.x, a.y, a.z, a.w};
      const float ww[4] = {w.x, w.y, w.z, w.w};
#pragma unroll
      for (int i = 0; i < 4; ++i)
#pragma unroll
        for (int j = 0; j < 4; ++j) acc[i][j] = fmaf(aa[i], ww[j], acc[i][j]);
    }
    __syncthreads();
  }
#pragma unroll
  for (int i = 0; i < 4; ++i) {
    const int grow = row0 + 4 * ty + i;
    const int b = grow >> 4, tt = tbase + (grow & 15);
    float* orow = outbase + (size_t)b * OUT_ROW + (size_t)tt * OUTFd + 1536;
#pragma unroll
    for (int j = 0; j < 4; ++j) {
      const int c = col0 + 4 * tx + j;
      orow[c] = acc[i][j] + pb2[c];
    }
  }
}

// ---------------------------------------------------------------------------
extern "C" void kernel_launch(void* const* d_in, const int* in_sizes, int n_in,
                              void* d_out, int out_size, void* d_ws, size_t ws_size,
                              hipStream_t stream) {
  const float* obs  = (const float*)d_in[0];
  const float* act  = (const float*)d_in[1];
  const float* w_ih = (const float*)d_in[2];
  const float* w_hh = (const float*)d_in[3];
  const float* b_ih = (const float*)d_in[4];
  const float* b_hh = (const float*)d_in[5];
  const float* pw1  = (const float*)d_in[6];
  const float* pb1  = (const float*)d_in[7];
  const float* pw2  = (const float*)d_in[8];
  const float* pb2  = (const float*)d_in[9];
  const float* qw1  = (const float*)d_in[10];
  const float* qb1  = (const float*)d_in[11];
  const float* qw2  = (const float*)d_in[12];
  const float* qb2  = (const float*)d_in[13];
  float* out = (float*)d_out;
  char* ws = (char*)d_ws;

  // workspace layout
  double*   deterA = (double*)(ws + 0);                 // 1 MiB
  double*   deterB = (double*)(ws + (1u << 20));        // 1 MiB
  double*   h1po   = (double*)(ws + (2u << 20));        // 1 MiB
  int*      sidx   = (int*)(ws + (3u << 20));           // 32 KiB
  float*    sval   = (float*)(ws + (3u << 20) + 32768); // 32 KiB
  uint32_t* keys   = (uint32_t*)(ws + (3u << 20) + 65536); // 1 KiB
  uint32_t* bar    = (uint32_t*)(ws + (3u << 20) + 66560); // 256 B barrier state
  float*    hbuf   = (float*)(ws + (4u << 20));         // 8 MiB (4096x512 f32)

  uint32_t* bar_cnt   = bar;       // [0]
  uint32_t* bar_sense = bar + 32;  // separate cacheline

  hipMemsetAsync(deterA, 0, 256 * 512 * 8, stream);
  hipMemsetAsync(sidx, 0, 256 * 32 * 4, stream);
  hipMemsetAsync(sval, 0, 256 * 32 * 4, stream);
  hipMemsetAsync(bar, 0, 256, stream);
  keys_k<<<1, 128, 0, stream>>>(keys);

  // whole sequential loop in ONE persistent kernel: 256 blocks (1/CU),
  // normal launch (graph-capture-safe), fence-free grid barrier.
  loop_k<<<dim3(NBLK), dim3(256), 0, stream>>>(
      obs, act, w_ih, w_hh, b_ih, b_hh, qw1, qb1, qw2, qb2, keys,
      deterA, deterB, h1po, sidx, sval, out, bar_cnt, bar_sense);

  // deferred prior head (f32), batched over 8 chunks of TC=16 timesteps
  for (int c = 0; c < Tt / TC; ++c) {
    prior1_k<<<dim3(8, 64), 256, 0, stream>>>(out, pw1, pb1, hbuf, c * TC);
    prior2_k<<<dim3(16, 64), 256, 0, stream>>>(hbuf, pw2, pb2, out, c * TC);
  }
}

// Round 8
// 14472.084 us; speedup vs baseline: 1.7344x; 1.4338x over previous
//
#include <hip/hip_runtime.h>
#include <stdint.h>

#define Tt 128
#define OBSd 768
#define ACTd 7
#define OUTFd 3584                 // 512 deter + 1024 stoch + 1024 prior + 1024 post
#define OUT_ROW (Tt * OUTFd)       // floats per batch row
#define TC 16                      // prior batch chunk (timesteps)
#define NBLK 256                   // persistent grid: 1 block per CU

// ---------------------------------------------------------------------------
// Threefry-2x32, exact JAX semantics (identical to round-1 — do not touch)
// ---------------------------------------------------------------------------
__device__ __forceinline__ uint32_t rotl32(uint32_t v, int r) {
  return (v << r) | (v >> (32 - r));
}

__device__ __forceinline__ void tf2x32(uint32_t key0, uint32_t key1,
                                       uint32_t x0, uint32_t x1,
                                       uint32_t& o0, uint32_t& o1) {
  uint32_t ks0 = key0, ks1 = key1, ks2 = key0 ^ key1 ^ 0x1BD11BDAu;
  x0 += ks0; x1 += ks1;
#define TFR(r) { x0 += x1; x1 = rotl32(x1, (r)); x1 ^= x0; }
  TFR(13) TFR(15) TFR(26) TFR(6)
  x0 += ks1; x1 += ks2 + 1u;
  TFR(17) TFR(29) TFR(16) TFR(24)
  x0 += ks2; x1 += ks0 + 2u;
  TFR(13) TFR(15) TFR(26) TFR(6)
  x0 += ks0; x1 += ks1 + 3u;
  TFR(17) TFR(29) TFR(16) TFR(24)
  x0 += ks1; x1 += ks2 + 4u;
  TFR(13) TFR(15) TFR(26) TFR(6)
  x0 += ks2; x1 += ks0 + 5u;
#undef TFR
  o0 = x0; o1 = x1;
}

__global__ __launch_bounds__(128) void keys_k(uint32_t* keys) {
  const int t = threadIdx.x;
  uint32_t o0, o1;
  tf2x32(0u, 42u, 0u, (uint32_t)t, o0, o1);
  keys[2 * t] = o0;
  keys[2 * t + 1] = o1;
}

// ---------------------------------------------------------------------------
// Relaxed agent-scope (sc1) accessors for cross-phase data (unchanged, r3).
// ---------------------------------------------------------------------------
__device__ __forceinline__ double ald(const double* p) {
  return __hip_atomic_load((double*)p, __ATOMIC_RELAXED, __HIP_MEMORY_SCOPE_AGENT);
}
__device__ __forceinline__ void ast(double* p, double v) {
  __hip_atomic_store(p, v, __ATOMIC_RELAXED, __HIP_MEMORY_SCOPE_AGENT);
}
__device__ __forceinline__ float alf(const float* p) {
  return __hip_atomic_load((float*)p, __ATOMIC_RELAXED, __HIP_MEMORY_SCOPE_AGENT);
}
__device__ __forceinline__ void asf(float* p, float v) {
  __hip_atomic_store(p, v, __ATOMIC_RELAXED, __HIP_MEMORY_SCOPE_AGENT);
}
__device__ __forceinline__ int ali(const int* p) {
  return __hip_atomic_load((int*)p, __ATOMIC_RELAXED, __HIP_MEMORY_SCOPE_AGENT);
}
__device__ __forceinline__ void asi(int* p, int v) {
  __hip_atomic_store(p, v, __ATOMIC_RELAXED, __HIP_MEMORY_SCOPE_AGENT);
}
__device__ __forceinline__ uint32_t alu(const uint32_t* p) {
  return __hip_atomic_load((uint32_t*)p, __ATOMIC_RELAXED, __HIP_MEMORY_SCOPE_AGENT);
}
__device__ __forceinline__ void asu(uint32_t* p, uint32_t v) {
  __hip_atomic_store(p, v, __ATOMIC_RELAXED, __HIP_MEMORY_SCOPE_AGENT);
}

// ---------------------------------------------------------------------------
// Flags grid barrier (epoch-based, NO single-address atomic serialization).
// Round-3's counter barrier cost ~35 us each: 256 fetch_adds to ONE fabric
// address serialize (~130 ns/RMW). Here: arrival = relaxed sc1 store to
// flags[bid] (256 distinct dwords -> stores pipeline); block 0's wave 0
// polls all 256 flags with 4 wave-wide loads + __all; lane 0 bumps the
// monotonic epoch; other blocks spin on epoch. Ordering: __syncthreads at
// entry drains each wave's vmem (compiler emits s_waitcnt vmcnt(0) before
// s_barrier), so all sc1 data stores are at the coherence point before the
// flag store issues.
// ---------------------------------------------------------------------------
__device__ __forceinline__ void gbar(uint32_t* flags, uint32_t* epoch,
                                     uint32_t e) {
  __syncthreads();
  const int tid = threadIdx.x;
  if (blockIdx.x == 0) {
    if (tid < 64) {
      if (tid == 0) asu(&flags[0], e);
      for (;;) {
        const uint32_t f0 = alu(&flags[tid]);
        const uint32_t f1 = alu(&flags[tid + 64]);
        const uint32_t f2 = alu(&flags[tid + 128]);
        const uint32_t f3 = alu(&flags[tid + 192]);
        const int ok = (f0 >= e) & (f1 >= e) & (f2 >= e) & (f3 >= e);
        if (__all(ok)) break;
        __builtin_amdgcn_s_sleep(1);
      }
      if (tid == 0) asu(epoch, e);
    }
  } else {
    if (tid == 0) {
      asu(&flags[blockIdx.x], e);
      while (alu(epoch) < e) __builtin_amdgcn_s_sleep(2);
    }
  }
  __syncthreads();
}

// ---------------------------------------------------------------------------
// Precompute gobs[t][b][j] = sum_k obs[b,t,k] * qw1[512+k][j]  (f64 accum).
// Deter-independent part of post1, hoisted out of the sequential loop.
// 64x64 tile, K=768, grid (8, 512). t-major output so each step's slice is
// a contiguous 1 MB block.
// ---------------------------------------------------------------------------
__global__ __launch_bounds__(256) void gobs_k(const float* __restrict__ obs,
                                              const float* __restrict__ qw1,
                                              double* __restrict__ gobs) {
  __shared__ float As[16][68];
  __shared__ float Ws[16][64];
  const int tid = threadIdx.x;
  const int tx = tid & 15, ty = tid >> 4;
  const int row0 = blockIdx.y * 64, col0 = blockIdx.x * 64;
  double acc[4][4] = {};
  const int sA = tid * 4;
  const int kkA = sA & 15, mA = sA >> 4;
  const int kkW = tid >> 4, nW = (tid & 15) * 4;
  const int grow = row0 + mA;                 // grow = b*128 + t
  const float* arow = obs + (size_t)grow * OBSd;
  for (int k0 = 0; k0 < OBSd; k0 += 16) {
    const float4 av = *(const float4*)(arow + k0 + kkA);
    As[kkA][mA] = av.x; As[kkA + 1][mA] = av.y;
    As[kkA + 2][mA] = av.z; As[kkA + 3][mA] = av.w;
    *(float4*)&Ws[kkW][nW] =
        *(const float4*)(qw1 + (size_t)(512 + k0 + kkW) * 512 + col0 + nW);
    __syncthreads();
#pragma unroll
    for (int kk = 0; kk < 16; ++kk) {
      const float4 a = *(const float4*)&As[kk][4 * ty];
      const float4 w = *(const float4*)&Ws[kk][4 * tx];
      const double aa[4] = {(double)a.x, (double)a.y, (double)a.z, (double)a.w};
      const double ww[4] = {(double)w.x, (double)w.y, (double)w.z, (double)w.w};
#pragma unroll
      for (int i = 0; i < 4; ++i)
#pragma unroll
        for (int j = 0; j < 4; ++j) acc[i][j] = fma(aa[i], ww[j], acc[i][j]);
    }
    __syncthreads();
  }
#pragma unroll
  for (int i = 0; i < 4; ++i) {
    const int r = row0 + 4 * ty + i;          // r = b*128 + t
    const int b = r >> 7, t = r & 127;
    double* orow = gobs + ((size_t)t * 256 + b) * 512;
#pragma unroll
    for (int j = 0; j < 4; ++j) orow[col0 + 4 * tx + j] = acc[i][j];
  }
}

// ---------------------------------------------------------------------------
// Persistent kernel: the entire T=128 sequential loop.
// 256 blocks x 256 threads (1 block/CU). Per step, 3 phases with flag barriers:
//   A: GRU   — gh = dprev @ w_hh (f64) + one-hot gather gi + gates -> deter
//   B: post1 — h1po = ELU(deter @ qw1[0:512] + gobs[t] + qb1), K=512 (+fallback)
//   C: post2 — logits = h1po @ qw2 + qb2 + gumbel-argmax sample (verbatim math)
// ---------------------------------------------------------------------------
__global__ __launch_bounds__(256) void loop_k(
    const float* __restrict__ obs, const float* __restrict__ act,
    const float* __restrict__ w_ih, const float* __restrict__ w_hh,
    const float* __restrict__ b_ih, const float* __restrict__ b_hh,
    const float* __restrict__ qw1, const float* __restrict__ qb1,
    const float* __restrict__ qw2, const float* __restrict__ qb2,
    const uint32_t* __restrict__ keys,
    double* __restrict__ deterA, double* __restrict__ deterB,
    double* __restrict__ h1po, int* __restrict__ sidx,
    float* __restrict__ sval, float* __restrict__ out,
    uint32_t* flags, uint32_t* epoch,
    const double* __restrict__ gobs, int use_gobs) {
  const int bid = blockIdx.x;
  const int tid = threadIdx.x;
  const int tx = tid & 15, ty = tid >> 4;
  uint32_t ep = 0;   // per-thread barrier epoch (identical across all threads)

  // phase A shared
  __shared__ double Aa[16][17];
  __shared__ double Wr[16][32], Wz[16][32], Wn[16][32];
  __shared__ int   sIdxL[16][32];
  __shared__ float sValL[16][32];
  __shared__ float actL[16][8];
  // phase B shared
  __shared__ double Ba[16][17];
  __shared__ double Bw[16][32];
  // phase C shared
  __shared__ double Ca[16][34];
  __shared__ double Cw[16][32];
  __shared__ double Ls[32][33];
  __shared__ int bcS[32];

  for (int t = 0; t < Tt; ++t) {
    double* dp = (t & 1) ? deterB : deterA;
    double* dn = (t & 1) ? deterA : deterB;

    // ================= phase A : GRU =================
    {
      const int row0 = (bid >> 4) * 16;
      const int col0 = (bid & 15) * 32;
      // stage sample indices/values + actions for this block's 16 rows
      {
        const int e = tid * 2;
        const int bl = e >> 5, s = e & 31;
        sIdxL[bl][s]     = ali(sidx + (row0 + bl) * 32 + s);
        sIdxL[bl][s + 1] = ali(sidx + (row0 + bl) * 32 + s + 1);
        sValL[bl][s]     = alf(sval + (row0 + bl) * 32 + s);
        sValL[bl][s + 1] = alf(sval + (row0 + bl) * 32 + s + 1);
        if (tid < 112) {
          const int bl2 = tid / 7, j2 = tid % 7;
          actL[bl2][j2] = act[((size_t)(row0 + bl2) * Tt + t) * ACTd + j2];
        }
      }
      double aR[2] = {}, aZ[2] = {}, aNi[2] = {}, aNh[2] = {};
      const int nW = tx * 2;
      // hoisted: previous-deter values for the gate blend (hides ~700cy sc1)
      const double dold0 = ald(dp + (size_t)(row0 + ty) * 512 + col0 + 2 * tx);
      const double dold1 = ald(dp + (size_t)(row0 + ty) * 512 + col0 + 2 * tx + 1);
      // prefetch k0 = 0
      double pA = ald(dp + (size_t)(row0 + ty) * 512 + tx);
      float2 pr, pz, pn;
      {
        const size_t wb = (size_t)ty * 1536 + col0 + nW;
        pr = *(const float2*)(w_hh + wb);
        pz = *(const float2*)(w_hh + wb + 512);
        pn = *(const float2*)(w_hh + wb + 1024);
      }
      for (int k0 = 0; k0 < 512; k0 += 16) {
        Aa[tx][ty] = pA;
        Wr[ty][nW] = pr.x; Wr[ty][nW + 1] = pr.y;
        Wz[ty][nW] = pz.x; Wz[ty][nW + 1] = pz.y;
        Wn[ty][nW] = pn.x; Wn[ty][nW + 1] = pn.y;
        __syncthreads();
        if (k0 + 16 < 512) {
          pA = ald(dp + (size_t)(row0 + ty) * 512 + k0 + 16 + tx);
          const size_t wb = (size_t)(k0 + 16 + ty) * 1536 + col0 + nW;
          pr = *(const float2*)(w_hh + wb);
          pz = *(const float2*)(w_hh + wb + 512);
          pn = *(const float2*)(w_hh + wb + 1024);
        }
#pragma unroll
        for (int kk = 0; kk < 16; ++kk) {
          const double a = Aa[kk][ty];
          const double2 wr = *(const double2*)&Wr[kk][2 * tx];
          const double2 wz = *(const double2*)&Wz[kk][2 * tx];
          const double2 wn = *(const double2*)&Wn[kk][2 * tx];
          aR[0] = fma(a, wr.x, aR[0]);   aR[1] = fma(a, wr.y, aR[1]);
          aZ[0] = fma(a, wz.x, aZ[0]);   aZ[1] = fma(a, wz.y, aZ[1]);
          aNh[0] = fma(a, wn.x, aNh[0]); aNh[1] = fma(a, wn.y, aNh[1]);
        }
        __syncthreads();
      }
      // gi gather: stoch is one-hot (forward value 1.0 to within 1e-16)
      for (int s = 0; s < 32; ++s) {
        const float v = sValL[ty][s];
        if (v != 0.0f) {
          const size_t wb = (size_t)(s * 32 + sIdxL[ty][s]) * 1536 + col0 + 2 * tx;
          const float2 f0 = *(const float2*)(w_ih + wb);
          const float2 f1 = *(const float2*)(w_ih + wb + 512);
          const float2 f2 = *(const float2*)(w_ih + wb + 1024);
          const double dv = (double)v;
          aR[0]  = fma(dv, (double)f0.x, aR[0]);  aR[1]  = fma(dv, (double)f0.y, aR[1]);
          aZ[0]  = fma(dv, (double)f1.x, aZ[0]);  aZ[1]  = fma(dv, (double)f1.y, aZ[1]);
          aNi[0] = fma(dv, (double)f2.x, aNi[0]); aNi[1] = fma(dv, (double)f2.y, aNi[1]);
        }
      }
      for (int j2 = 0; j2 < 7; ++j2) {
        const double av = (double)actL[ty][j2];
        const size_t wb = (size_t)(1024 + j2) * 1536 + col0 + 2 * tx;
        const float2 f0 = *(const float2*)(w_ih + wb);
        const float2 f1 = *(const float2*)(w_ih + wb + 512);
        const float2 f2 = *(const float2*)(w_ih + wb + 1024);
        aR[0]  = fma(av, (double)f0.x, aR[0]);  aR[1]  = fma(av, (double)f0.y, aR[1]);
        aZ[0]  = fma(av, (double)f1.x, aZ[0]);  aZ[1]  = fma(av, (double)f1.y, aZ[1]);
        aNi[0] = fma(av, (double)f2.x, aNi[0]); aNi[1] = fma(av, (double)f2.y, aNi[1]);
      }
      // gates
      {
        const int b = row0 + ty;
        const size_t obase = (size_t)b * OUT_ROW + (size_t)t * OUTFd;
#pragma unroll
        for (int cb = 0; cb < 2; ++cb) {
          const int jj = col0 + 2 * tx + cb;
          const double dold = cb ? dold1 : dold0;
          const double xr = aR[cb] + (double)b_ih[jj] + (double)b_hh[jj];
          const double xz = aZ[cb] + (double)b_ih[512 + jj] + (double)b_hh[512 + jj];
          const double r = 1.0 / (1.0 + exp(-xr));
          const double z = 1.0 / (1.0 + exp(-xz));
          const double n = tanh(aNi[cb] + (double)b_ih[1024 + jj] +
                                r * (aNh[cb] + (double)b_hh[1024 + jj]));
          const double dnv = (1.0 - z) * n + z * dold;
          ast(dn + (size_t)b * 512 + jj, dnv);
          out[obase + jj] = (float)dnv;
        }
      }
    }
    gbar(flags, epoch, ++ep);

    // ================= phase B : post1 =================
    {
      const int row0 = (bid >> 4) * 16;
      const int col0 = (bid & 15) * 32;
      const int nW = tx * 2;
      const int cc = col0 + 2 * tx;
      // hoisted gobs (precomputed obs-part); plain cached load, t-major slice
      double gb0 = 0.0, gb1 = 0.0;
      if (use_gobs) {
        const double2 g =
            *(const double2*)(gobs + ((size_t)t * 256 + row0 + ty) * 512 + cc);
        gb0 = g.x; gb1 = g.y;
      }
      const int KB = use_gobs ? 512 : 1280;
      double a0 = 0.0, a1 = 0.0;
      // prefetch k0 = 0 (k<512 -> deter part)
      double pA = ald(dn + (size_t)(row0 + ty) * 512 + tx);
      float2 pW = *(const float2*)(qw1 + (size_t)ty * 512 + col0 + nW);
      for (int k0 = 0; k0 < KB; k0 += 16) {
        Ba[tx][ty] = pA;
        Bw[ty][nW] = (double)pW.x; Bw[ty][nW + 1] = (double)pW.y;
        __syncthreads();
        if (k0 + 16 < KB) {
          const int gc = k0 + 16 + tx;
          const int gr = row0 + ty;
          pA = (gc < 512)
                   ? ald(dn + (size_t)gr * 512 + gc)
                   : (double)obs[((size_t)gr * Tt + t) * OBSd + (gc - 512)];
          pW = *(const float2*)(qw1 + (size_t)(k0 + 16 + ty) * 512 + col0 + nW);
        }
#pragma unroll
        for (int kk = 0; kk < 16; ++kk) {
          const double a = Ba[kk][ty];
          const double2 w = *(const double2*)&Bw[kk][2 * tx];
          a0 = fma(a, w.x, a0);
          a1 = fma(a, w.y, a1);
        }
        __syncthreads();
      }
      double v0 = a0 + gb0 + (double)qb1[cc];
      double v1 = a1 + gb1 + (double)qb1[cc + 1];
      v0 = v0 > 0.0 ? v0 : expm1(v0);
      v1 = v1 > 0.0 ? v1 : expm1(v1);
      ast(h1po + (size_t)(row0 + ty) * 512 + cc, v0);
      ast(h1po + (size_t)(row0 + ty) * 512 + cc + 1, v1);
    }
    gbar(flags, epoch, ++ep);

    // ================= phase C : post2 + sample =================
    {
      const int row0 = (bid >> 5) * 32;
      const int s = bid & 31;
      const int col0 = s * 32;
      const int sA = tid * 2;
      const int kkA = sA & 15, mA = sA >> 4;
      const int kkW = sA >> 5, nW2 = sA & 31;
      double a00 = 0, a01 = 0, a10 = 0, a11 = 0;
      // issue first-chunk prefetch, then overlap gumbel VALU with its latency
      double pH0 = ald(h1po + (size_t)(row0 + mA) * 512 + kkA);
      double pH1 = ald(h1po + (size_t)(row0 + mA) * 512 + kkA + 1);
      float2 pW = *(const float2*)(qw2 + (size_t)kkW * 1024 + col0 + nW2);
      // gumbel precompute (depends only on b,col,t — EXACT round-1 formula)
      const uint32_t key0 = keys[2 * t], key1 = keys[2 * t + 1];
      double gum[2][2];
#pragma unroll
      for (int rb = 0; rb < 2; ++rb) {
        const int b = row0 + 2 * ty + rb;
#pragma unroll
        for (int cb = 0; cb < 2; ++cb) {
          const int col = col0 + 2 * tx + cb;
          uint32_t o0, o1;
          tf2x32(key0, key1, 0u, (uint32_t)(b * 1024 + col), o0, o1);
          const uint32_t bits = o0 ^ o1;
          const uint32_t m = bits >> 9;
          const float uf = __uint_as_float(m | 0x3f800000u) - 1.0f;
          const double u = (m == 0u) ? (double)1.17549435e-38f : (double)uf;
          gum[rb][cb] = -log(-log(u));
        }
      }
      for (int k0 = 0; k0 < 512; k0 += 16) {
        Ca[kkA][mA] = pH0; Ca[kkA + 1][mA] = pH1;
        Cw[kkW][nW2] = (double)pW.x; Cw[kkW][nW2 + 1] = (double)pW.y;
        __syncthreads();
        if (k0 + 16 < 512) {
          pH0 = ald(h1po + (size_t)(row0 + mA) * 512 + k0 + 16 + kkA);
          pH1 = ald(h1po + (size_t)(row0 + mA) * 512 + k0 + 16 + kkA + 1);
          pW = *(const float2*)(qw2 + (size_t)(k0 + 16 + kkW) * 1024 + col0 + nW2);
        }
#pragma unroll
        for (int kk = 0; kk < 16; ++kk) {
          const double2 av = *(const double2*)&Ca[kk][2 * ty];
          const double2 wv2 = *(const double2*)&Cw[kk][2 * tx];
          a00 = fma(av.x, wv2.x, a00); a01 = fma(av.x, wv2.y, a01);
          a10 = fma(av.y, wv2.x, a10); a11 = fma(av.y, wv2.y, a11);
        }
        __syncthreads();
      }
      double accv[2][2] = {{a00, a01}, {a10, a11}};
#pragma unroll
      for (int rb = 0; rb < 2; ++rb) {
        const int b = row0 + 2 * ty + rb;
#pragma unroll
        for (int cb = 0; cb < 2; ++cb) {
          const int col = col0 + 2 * tx + cb;
          const double l = accv[rb][cb] + (double)qb2[col];
          out[(size_t)b * OUT_ROW + (size_t)t * OUTFd + 2560 + col] = (float)l;
          Ls[2 * ty + rb][2 * tx + cb] = l + gum[rb][cb];
        }
      }
      __syncthreads();
      if (tid < 32) {
        const int bl = tid;
        double best = -1.0e300;
        int bc = 0;
        for (int c = 0; c < 32; ++c) {
          const double v = Ls[bl][c];
          if (v > best) { best = v; bc = c; }   // strict >: first-index ties
        }
        bcS[bl] = bc;
        const int b = row0 + bl;
        asi(sidx + b * 32 + s, bc);
        asf(sval + b * 32 + s, 1.0f);
      }
      __syncthreads();
#pragma unroll
      for (int rb = 0; rb < 2; ++rb) {
        const int b = row0 + 2 * ty + rb;
        const int bc = bcS[2 * ty + rb];
#pragma unroll
        for (int cb = 0; cb < 2; ++cb) {
          const int c = 2 * tx + cb;
          out[(size_t)b * OUT_ROW + (size_t)t * OUTFd + 512 + col0 + c] =
              (c == bc) ? 1.0f : 0.0f;
        }
      }
    }
    if (t != Tt - 1) gbar(flags, epoch, ++ep);
  }
}

// ---------------------------------------------------------------------------
// Deferred prior head, f32, batched over (b, t) chunks of TC timesteps.
// (unchanged, verified)
// ---------------------------------------------------------------------------
__global__ __launch_bounds__(256) void prior1_k(const float* __restrict__ outbase,
                                                const float* __restrict__ pw1,
                                                const float* __restrict__ pb1,
                                                float* __restrict__ hbuf, int tbase) {
  __shared__ float As[16][68];
  __shared__ float Ws[16][64];
  const int tid = threadIdx.x;
  const int tx = tid & 15, ty = tid >> 4;
  const int row0 = blockIdx.y * 64, col0 = blockIdx.x * 64;
  float acc[4][4] = {};
  const int sA = tid * 4;
  const int kkA = sA & 15, mA = sA >> 4;
  const int kkW = tid >> 4, nW = (tid & 15) * 4;
  const int grow = row0 + mA;
  const int b = grow >> 4, tt = tbase + (grow & 15);
  const float* arow = outbase + (size_t)b * OUT_ROW + (size_t)tt * OUTFd;
  for (int k0 = 0; k0 < 512; k0 += 16) {
    const float4 av = *(const float4*)(arow + k0 + kkA);
    As[kkA][mA] = av.x; As[kkA + 1][mA] = av.y;
    As[kkA + 2][mA] = av.z; As[kkA + 3][mA] = av.w;
    *(float4*)&Ws[kkW][nW] = *(const float4*)(pw1 + (size_t)(k0 + kkW) * 512 + col0 + nW);
    __syncthreads();
#pragma unroll
    for (int kk = 0; kk < 16; ++kk) {
      const float4 a = *(const float4*)&As[kk][4 * ty];
      const float4 w = *(const float4*)&Ws[kk][4 * tx];
      const float aa[4] = {a.x, a.y, a.z, a.w};
      const float ww[4] = {w.x, w.y, w.z, w.w};
#pragma unroll
      for (int i = 0; i < 4; ++i)
#pragma unroll
        for (int j = 0; j < 4; ++j) acc[i][j] = fmaf(aa[i], ww[j], acc[i][j]);
    }
    __syncthreads();
  }
#pragma unroll
  for (int i = 0; i < 4; ++i) {
    const int r = row0 + 4 * ty + i;
#pragma unroll
    for (int j = 0; j < 4; ++j) {
      const int c = col0 + 4 * tx + j;
      float x = acc[i][j] + pb1[c];
      x = x > 0.f ? x : expm1f(x);
      hbuf[(size_t)r * 512 + c] = x;
    }
  }
}

__global__ __launch_bounds__(256) void prior2_k(const float* __restrict__ hbuf,
                                                const float* __restrict__ pw2,
                                                const float* __restrict__ pb2,
                                                float* __restrict__ outbase, int tbase) {
  __shared__ float As[16][68];
  __shared__ float Ws[16][64];
  const int tid = threadIdx.x;
  const int tx = tid & 15, ty = tid >> 4;
  const int row0 = blockIdx.y * 64, col0 = blockIdx.x * 64;
  float acc[4][4] = {};
  const int sA = tid * 4;
  const int kkA = sA & 15, mA = sA >> 4;
  const int kkW = tid >> 4, nW = (tid & 15) * 4;
  for (int k0 = 0; k0 < 512; k0 += 16) {
    const float4 av = *(const float4*)(hbuf + (size_t)(row0 + mA) * 512 + k0 + kkA);
    As[kkA][mA] = av.x; As[kkA + 1][mA] = av.y;
    As[kkA + 2][mA] = av.z; As[kkA + 3][mA] = av.w;
    *(float4*)&Ws[kkW][nW] = *(const float4*)(pw2 + (size_t)(k0 + kkW) * 1024 + col0 + nW);
    __syncthreads();
#pragma unroll
    for (int kk = 0; kk < 16; ++kk) {
      const float4 a = *(const float4*)&As[kk][4 * ty];
      const float4 w = *(const float4*)&Ws[kk][4 * tx];
      const float aa[4] = {a.x, a.y, a.z, a.w};
      const float ww[4] = {w.x, w.y, w.z, w.w};
#pragma unroll
      for (int i = 0; i < 4; ++i)
#pragma unroll
        for (int j = 0; j < 4; ++j) acc[i][j] = fmaf(aa[i], ww[j], acc[i][j]);
    }
    __syncthreads();
  }
#pragma unroll
  for (int i = 0; i < 4; ++i) {
    const int grow = row0 + 4 * ty + i;
    const int b = grow >> 4, tt = tbase + (grow & 15);
    float* orow = outbase + (size_t)b * OUT_ROW + (size_t)tt * OUTFd + 1536;
#pragma unroll
    for (int j = 0; j < 4; ++j) {
      const int c = col0 + 4 * tx + j;
      orow[c] = acc[i][j] + pb2[c];
    }
  }
}

// ---------------------------------------------------------------------------
extern "C" void kernel_launch(void* const* d_in, const int* in_sizes, int n_in,
                              void* d_out, int out_size, void* d_ws, size_t ws_size,
                              hipStream_t stream) {
  const float* obs  = (const float*)d_in[0];
  const float* act  = (const float*)d_in[1];
  const float* w_ih = (const float*)d_in[2];
  const float* w_hh = (const float*)d_in[3];
  const float* b_ih = (const float*)d_in[4];
  const float* b_hh = (const float*)d_in[5];
  const float* pw1  = (const float*)d_in[6];
  const float* pb1  = (const float*)d_in[7];
  const float* pw2  = (const float*)d_in[8];
  const float* pb2  = (const float*)d_in[9];
  const float* qw1  = (const float*)d_in[10];
  const float* qb1  = (const float*)d_in[11];
  const float* qw2  = (const float*)d_in[12];
  const float* qb2  = (const float*)d_in[13];
  float* out = (float*)d_out;
  char* ws = (char*)d_ws;

  // workspace layout
  double*   deterA = (double*)(ws + 0);                 // 1 MiB
  double*   deterB = (double*)(ws + (1u << 20));        // 1 MiB
  double*   h1po   = (double*)(ws + (2u << 20));        // 1 MiB
  int*      sidx   = (int*)(ws + (3u << 20));           // 32 KiB
  float*    sval   = (float*)(ws + (3u << 20) + 32768); // 32 KiB
  uint32_t* keys   = (uint32_t*)(ws + (3u << 20) + 65536); // 1 KiB
  uint32_t* flags  = (uint32_t*)(ws + (3u << 20) + 66560); // 1 KiB barrier flags
  uint32_t* epoch  = (uint32_t*)(ws + (3u << 20) + 66560 + 1024); // own line
  float*    hbuf   = (float*)(ws + (4u << 20));         // 8 MiB (4096x512 f32)
  double*   gobs   = (double*)(ws + (16ull << 20));     // 134 MiB (optional)

  const size_t gobs_bytes = 256ull * 128 * 512 * 8;
  const int use_gobs = (ws_size >= (16ull << 20) + gobs_bytes) ? 1 : 0;

  hipMemsetAsync(deterA, 0, 256 * 512 * 8, stream);
  hipMemsetAsync(sidx, 0, 256 * 32 * 4, stream);
  hipMemsetAsync(sval, 0, 256 * 32 * 4, stream);
  hipMemsetAsync(flags, 0, 1024 + 128, stream);
  keys_k<<<1, 128, 0, stream>>>(keys);

  // hoisted obs-part of post1 (parallel, fills gobs once)
  if (use_gobs) gobs_k<<<dim3(8, 512), 256, 0, stream>>>(obs, qw1, gobs);

  // whole sequential loop in ONE persistent kernel: 256 blocks (1/CU),
  // normal launch (graph-capture-safe), flags-based grid barrier.
  loop_k<<<dim3(NBLK), dim3(256), 0, stream>>>(
      obs, act, w_ih, w_hh, b_ih, b_hh, qw1, qb1, qw2, qb2, keys,
      deterA, deterB, h1po, sidx, sval, out, flags, epoch, gobs, use_gobs);

  // deferred prior head (f32), batched over 8 chunks of TC=16 timesteps
  for (int c = 0; c < Tt / TC; ++c) {
    prior1_k<<<dim3(8, 64), 256, 0, stream>>>(out, pw1, pb1, hbuf, c * TC);
    prior2_k<<<dim3(16, 64), 256, 0, stream>>>(hbuf, pw2, pb2, out, c * TC);
  }
}